// Round 4
// baseline (415.327 us; speedup 1.0000x reference)
//
#include <hip/hip_runtime.h>
#include <math.h>

#define BB 32
#define NN 1024
#define FF 64
#define PP 128
#define KNN 16
#define H2 256  // 2P
#define F2 128  // 2F
#define KSEL 17
#define SVCAP 272

typedef float f32x4 __attribute__((ext_vector_type(4)));
typedef __bf16 bf16x8 __attribute__((ext_vector_type(8)));

__device__ __forceinline__ float gelu_fast(float x) {
    float u = x * (1.0f + 0.044715f * x * x);
    float e = __builtin_amdgcn_exp2f(-2.3022115f * u);
    return x * __builtin_amdgcn_rcpf(1.0f + e);
}

// ---------------- Kernel A: set-based kNN via radix ballot-select -------------------
__global__ __launch_bounds__(512, 8) void knn_select(const float* __restrict__ points,
                                                     int* __restrict__ idx_out) {
    __shared__ float4 pts[NN];
    __shared__ unsigned sv_val[8][SVCAP];
    __shared__ unsigned sv_idx[8][SVCAP];
    __shared__ unsigned tie_idx[8][64];

    const int t = threadIdx.x;
    const int w = t >> 6, lane = t & 63;
    const int b = blockIdx.x >> 7;
    const int q0 = (blockIdx.x & 127) * 8;
    const float* pb = points + (size_t)b * NN * 3;
    const unsigned long long lt = (1ull << lane) - 1ull;

    for (int i = t; i < NN; i += 512) {
        float x = pb[3 * i], y = pb[3 * i + 1], z = pb[3 * i + 2];
        float r = __fadd_rn(__fadd_rn(__fmul_rn(x, x), __fmul_rn(y, y)), __fmul_rn(z, z));
        pts[i] = make_float4(x, y, z, r);
    }
    __syncthreads();

    const int qn = q0 + w;
    const int gq = b * NN + qn;
    const float4 qp = pts[qn];

    float D[16];
#pragma unroll
    for (int j = 0; j < 16; ++j) {
        float4 c = pts[j * 64 + lane];
        float dot = __fadd_rn(__fadd_rn(__fmul_rn(qp.x, c.x), __fmul_rn(qp.y, c.y)),
                              __fmul_rn(qp.z, c.z));
        D[j] = __fadd_rn(__fadd_rn(__fsub_rn(qp.w, __fmul_rn(2.0f, dot)), c.w), 1e-5f);
    }

    float mnf = D[0];
#pragma unroll
    for (int j = 1; j < 16; ++j) mnf = fminf(mnf, D[j]);
    const unsigned mbits = __float_as_uint(mnf);

    unsigned T = 0;
#pragma unroll
    for (int bit = 31; bit >= 0; --bit) {
        unsigned cand = T | (1u << bit);
        int cnt = __popcll(__ballot(mbits < cand));
        if (cnt < KSEL) T = cand;
    }

    // ---- compact survivors (<= T) via ballot prefix-rank (no atomics) ----
    unsigned base = 0;
#pragma unroll
    for (int j = 0; j < 16; ++j) {
        unsigned vb = __float_as_uint(D[j]);
        bool keep = (vb <= T);
        unsigned long long m = __ballot(keep);
        if (keep) {
            unsigned pos = base + (unsigned)__popcll(m & lt);
            if (pos < SVCAP) { sv_val[w][pos] = vb; sv_idx[w][pos] = j * 64 + lane; }
        }
        base += (unsigned)__popcll(m);
    }
    unsigned C = base > SVCAP ? SVCAP : base;
    const int S = (int)((C + 63) >> 6);

    // ---- T* = exact 17th smallest survivor ----
    unsigned Ts = 0;
    if (S == 1) {
        unsigned xv0 = (lane < (int)C) ? sv_val[w][lane] : 0xFFFFFFFFu;
#pragma unroll
        for (int bit = 31; bit >= 0; --bit) {
            unsigned cand = Ts | (1u << bit);
            int cnt = __popcll(__ballot(xv0 < cand));
            if (cnt < KSEL) Ts = cand;
        }
    } else {
        for (int bit = 31; bit >= 0; --bit) {
            unsigned cand = Ts | (1u << bit);
            int cnt = 0;
            for (int s = 0; s < S; ++s) {
                int i = s * 64 + lane;
                unsigned vb = (i < (int)C) ? sv_val[w][i] : 0xFFFFFFFFu;
                cnt += __popcll(__ballot(vb < cand));
            }
            if (cnt < KSEL) Ts = cand;
        }
    }

    int L = 0;
    for (int s = 0; s < S; ++s) {
        int i = s * 64 + lane;
        unsigned vb = (i < (int)C) ? sv_val[w][i] : 0xFFFFFFFFu;
        L += __popcll(__ballot(vb < Ts));
    }
    const int need = KSEL - L;

    // ---- dropIdx = lexicographic-min (val, idx) of top-17 == numpy rank 0 ----
    unsigned vmin_l = 0xFFFFFFFFu;
    for (int s = 0; s < S; ++s) {
        int i = s * 64 + lane;
        unsigned vb = (i < (int)C) ? sv_val[w][i] : 0xFFFFFFFFu;
        vmin_l = vmin_l < vb ? vmin_l : vb;
    }
#pragma unroll
    for (int off = 32; off >= 1; off >>= 1) {
        unsigned o2 = __shfl_xor(vmin_l, off, 64);
        vmin_l = vmin_l < o2 ? vmin_l : o2;
    }
    const unsigned Vmin = vmin_l;
    unsigned imin_l = 0xFFFFFFFFu;
    for (int s = 0; s < S; ++s) {
        int i = s * 64 + lane;
        unsigned vb = (i < (int)C) ? sv_val[w][i] : 0xFFFFFFFFu;
        unsigned mi = (i < (int)C) ? sv_idx[w][i] : 0xFFFFFFFFu;
        if (vb == Vmin && mi < imin_l) imin_l = mi;
    }
#pragma unroll
    for (int off = 32; off >= 1; off >>= 1) {
        unsigned o2 = __shfl_xor(imin_l, off, 64);
        imin_l = imin_l < o2 ? imin_l : o2;
    }
    const unsigned dropIdx = imin_l;

    // ---- emit: sure-includes (<T*, != drop) + ties (==T*), ballot-ranked ----
    int* o = idx_out + (size_t)gq * KNN;
    unsigned wbase = 0, tbase = 0;
    for (int s = 0; s < S; ++s) {
        int i = s * 64 + lane;
        unsigned vb = (i < (int)C) ? sv_val[w][i] : 0xFFFFFFFFu;
        unsigned mi = (i < (int)C) ? sv_idx[w][i] : 0xFFFFFFFFu;
        bool wk = (vb < Ts) && (mi != dropIdx);
        unsigned long long wm = __ballot(wk);
        if (wk) o[wbase + (unsigned)__popcll(wm & lt)] = (int)mi;
        wbase += (unsigned)__popcll(wm);
        bool tk = (vb == Ts);
        unsigned long long tm2 = __ballot(tk);
        if (tk) {
            unsigned tp = tbase + (unsigned)__popcll(tm2 & lt);
            if (tp < 64) tie_idx[w][tp] = mi;
        }
        tbase += (unsigned)__popcll(tm2);
    }
    unsigned tc = tbase > 64 ? 64 : tbase;
    if ((int)tc == need) {
        bool tk = (lane < (int)tc);
        unsigned mi2 = tk ? tie_idx[w][lane] : 0xFFFFFFFFu;
        tk = tk && (mi2 != dropIdx);
        unsigned long long m3 = __ballot(tk);
        if (tk) o[wbase + (unsigned)__popcll(m3 & lt)] = (int)mi2;
    } else if (lane == 0) {
        unsigned pos = wbase;
        for (int r = 0; r < need; ++r) {
            unsigned best = 0xFFFFFFFFu; int bj = 0;
            for (int j2 = 0; j2 < (int)tc; ++j2) {
                unsigned mi = tie_idx[w][j2];
                if (mi < best) { best = mi; bj = j2; }
            }
            tie_idx[w][bj] = 0xFFFFFFFFu;
            if (best != dropIdx) o[pos++] = (int)best;
        }
    }
}

// ---------------- prep_small: WcatT (512x64) + W2t (128x256), bf16 ------------------
// WcatT[n][k]: n<256 -> W1[k][n];  n>=256 -> W1[64+k][n-256] - W1[k][n-256]
__global__ __launch_bounds__(256) void prep_small(const float* __restrict__ W1,
                                                  const float* __restrict__ W2,
                                                  __bf16* __restrict__ WcatT,
                                                  __bf16* __restrict__ W2t) {
    int t = blockIdx.x * 256 + threadIdx.x;   // 0..32767
    {   int n = t >> 6, k = t & 63;
        float v = (n < 256) ? W1[k * 256 + n]
                            : (W1[(64 + k) * 256 + (n - 256)] - W1[k * 256 + (n - 256)]);
        WcatT[t] = (__bf16)v; }
    {   int h = t >> 7, p = t & 127;
        W2t[p * H2 + h] = (__bf16)W2[t]; }
}

// ---------------- gq_gemm: G = feat@W1a (bf16), Q = feat@Wd + b1 --------------------
// M=32768 rows, K=64, N=512. Block = 16 rows x 512 cols, wave = 16 x 128.
template<bool QF32>
__global__ __launch_bounds__(256, 4) void gq_gemm(const float* __restrict__ feat,
                                                  const __bf16* __restrict__ WcatT,
                                                  const float* __restrict__ b1,
                                                  __bf16* __restrict__ Gall,
                                                  void* __restrict__ Qall) {
    const int t = threadIdx.x, w = t >> 6, lane = t & 63;
    const int quad = lane >> 4, l16 = lane & 15;
    const int m0 = blockIdx.x * 16;
    const int strip = w * 128;

    bf16x8 a[2];
#pragma unroll
    for (int kk = 0; kk < 2; ++kk) {
        const float* ap = feat + (size_t)(m0 + l16) * 64 + kk * 32 + quad * 8;
        float4 a0 = *(const float4*)ap, a1 = *(const float4*)(ap + 4);
        bf16x8 v;
        v[0] = (__bf16)a0.x; v[1] = (__bf16)a0.y; v[2] = (__bf16)a0.z; v[3] = (__bf16)a0.w;
        v[4] = (__bf16)a1.x; v[5] = (__bf16)a1.y; v[6] = (__bf16)a1.z; v[7] = (__bf16)a1.w;
        a[kk] = v;
    }
    f32x4 acc[8];
#pragma unroll
    for (int nt = 0; nt < 8; ++nt) acc[nt] = (f32x4){0.f, 0.f, 0.f, 0.f};
#pragma unroll
    for (int kk = 0; kk < 2; ++kk)
#pragma unroll
        for (int nt = 0; nt < 8; ++nt) {
            bf16x8 bf = *(const bf16x8*)(WcatT + (size_t)(strip + nt * 16 + l16) * 64
                                         + kk * 32 + quad * 8);
            acc[nt] = __builtin_amdgcn_mfma_f32_16x16x32_bf16(a[kk], bf, acc[nt], 0, 0, 0);
        }
#pragma unroll
    for (int nt = 0; nt < 8; ++nt) {
        const int col = strip + nt * 16 + l16;
#pragma unroll
        for (int r = 0; r < 4; ++r) {
            const int m = m0 + quad * 4 + r;
            float v = acc[nt][r];
            if (col < 256) {
                Gall[(size_t)m * H2 + col] = (__bf16)v;
            } else {
                const int qc = col - 256;
                v += b1[qc];
                if (QF32) ((float*)Qall)[(size_t)m * H2 + qc] = v;
                else      ((__bf16*)Qall)[(size_t)m * H2 + qc] = (__bf16)v;
            }
        }
    }
}

// ---------------- fused_mlp2: out = mean_k gelu(gelu(G[idx]+Q) @ W2 + b2) ----------
// One wave = one query (16 neighbor rows). No LDS, no barriers.
template<bool QF32>
__global__ __launch_bounds__(256, 4) void fused_mlp2(const __bf16* __restrict__ Gall,
                                                     const void* __restrict__ Qall,
                                                     const int* __restrict__ knn_idx,
                                                     const __bf16* __restrict__ W2t,
                                                     const float* __restrict__ b2,
                                                     float* __restrict__ out) {
    const int t = threadIdx.x, w = t >> 6, lane = t & 63;
    const int quad = lane >> 4, l16 = lane & 15;
    const int gq = blockIdx.x * 4 + w;
    const int b = gq >> 10;

    const int nb = knn_idx[gq * KNN + l16];          // neighbor k = l16
    const size_t grow = ((size_t)(b << 10) + nb) * H2;
    const size_t qrow = (size_t)gq * H2;

    f32x4 acc[8];
#pragma unroll
    for (int nt = 0; nt < 8; ++nt) acc[nt] = (f32x4){0.f, 0.f, 0.f, 0.f};

#pragma unroll
    for (int half = 0; half < 2; ++half) {
        const int hbase = half * PP;
        bf16x8 af[4];
#pragma unroll
        for (int kk = 0; kk < 4; ++kk) {
            const int ho = hbase + kk * 32 + quad * 8;
            bf16x8 g8 = *(const bf16x8*)(Gall + grow + ho);
            float qv[8];
            if (QF32) {
                const float* qp = (const float*)Qall + qrow + ho;
                float4 q0 = *(const float4*)qp, q1 = *(const float4*)(qp + 4);
                qv[0] = q0.x; qv[1] = q0.y; qv[2] = q0.z; qv[3] = q0.w;
                qv[4] = q1.x; qv[5] = q1.y; qv[6] = q1.z; qv[7] = q1.w;
            } else {
                bf16x8 q8 = *(const bf16x8*)((const __bf16*)Qall + qrow + ho);
#pragma unroll
                for (int i = 0; i < 8; ++i) qv[i] = (float)q8[i];
            }
            bf16x8 a;
#pragma unroll
            for (int i = 0; i < 8; ++i)
                a[i] = (__bf16)gelu_fast((float)g8[i] + qv[i]);
            af[kk] = a;
        }
#pragma unroll
        for (int kk = 0; kk < 4; ++kk) {
            const int ho = hbase + kk * 32 + quad * 8;
#pragma unroll
            for (int nt = 0; nt < 8; ++nt) {
                bf16x8 bf = *(const bf16x8*)(W2t + (size_t)(nt * 16 + l16) * H2 + ho);
                acc[nt] = __builtin_amdgcn_mfma_f32_16x16x32_bf16(af[kk], bf, acc[nt], 0, 0, 0);
            }
        }
    }

#pragma unroll
    for (int nt = 0; nt < 8; ++nt) {
        const int p = nt * 16 + l16;
        const float bias = b2[p];
        float s = 0.f;
#pragma unroll
        for (int r = 0; r < 4; ++r) s += gelu_fast(acc[nt][r] + bias);
        s += __shfl_xor(s, 16, 64);
        s += __shfl_xor(s, 32, 64);
        if (quad == 0) out[(size_t)gq * PP + p] = s * 0.0625f;
    }
}

// ---------------- Fallback (round-3) path: prep_weights + mlp_mfma ------------------
__global__ __launch_bounds__(256) void prep_weights(const float* __restrict__ W1,
                                                    const float* __restrict__ W2,
                                                    __bf16* __restrict__ W1t,
                                                    __bf16* __restrict__ W2t) {
    int t = blockIdx.x * 256 + threadIdx.x;
    {   int f = t >> 8, h = t & 255;
        W1t[h * F2 + f] = (__bf16)W1[t]; }
    {   int h = t >> 7, p = t & 127;
        W2t[p * H2 + h] = (__bf16)W2[t]; }
}

#define XPITCH 136
__global__ __launch_bounds__(256) void mlp_mfma(const float* __restrict__ features,
                                                const int* __restrict__ knn_idx,
                                                const __bf16* __restrict__ W1t,
                                                const float* __restrict__ b1,
                                                const __bf16* __restrict__ W2t,
                                                const float* __restrict__ b2,
                                                float* __restrict__ out) {
    __shared__ __bf16 Xs[64][XPITCH];
    __shared__ __bf16 Hs[64][XPITCH];
    const int t = threadIdx.x;
    const int w = t >> 6, lane = t & 63;
    const int quad = lane >> 4, l16 = lane & 15;
    const int gq0 = blockIdx.x * 4;
    const int b = gq0 >> 10;
    {
        const int r = t >> 2;
        const int ql = r >> 4, k = r & 15;
        const int gq = gq0 + ql;
        const int nq = gq & 1023;
        const int nb = knn_idx[gq * KNN + k];
        const float* nrow = features + ((size_t)b * NN + nb) * FF;
        const float* crow = features + ((size_t)b * NN + nq) * FF;
        const int f0 = (t & 3) * 16;
#pragma unroll
        for (int i = 0; i < 4; ++i) {
            float4 nv = *(const float4*)(nrow + f0 + i * 4);
            float4 cv = *(const float4*)(crow + f0 + i * 4);
            Xs[r][f0 + i*4 + 0] = (__bf16)(nv.x - cv.x);
            Xs[r][f0 + i*4 + 1] = (__bf16)(nv.y - cv.y);
            Xs[r][f0 + i*4 + 2] = (__bf16)(nv.z - cv.z);
            Xs[r][f0 + i*4 + 3] = (__bf16)(nv.w - cv.w);
            Xs[r][FF + f0 + i*4 + 0] = (__bf16)cv.x;
            Xs[r][FF + f0 + i*4 + 1] = (__bf16)cv.y;
            Xs[r][FF + f0 + i*4 + 2] = (__bf16)cv.z;
            Xs[r][FF + f0 + i*4 + 3] = (__bf16)cv.w;
        }
    }
    __syncthreads();
    const int ncol0 = w * 32;
    f32x4 acc2[4][2];
#pragma unroll
    for (int tm = 0; tm < 4; ++tm)
#pragma unroll
        for (int nt = 0; nt < 2; ++nt) acc2[tm][nt] = (f32x4){0.f, 0.f, 0.f, 0.f};
#pragma unroll
    for (int half = 0; half < 2; ++half) {
        const int hbase = half * PP;
        f32x4 acc1[4][2];
#pragma unroll
        for (int tm = 0; tm < 4; ++tm)
#pragma unroll
            for (int nt = 0; nt < 2; ++nt) acc1[tm][nt] = (f32x4){0.f, 0.f, 0.f, 0.f};
#pragma unroll
        for (int kk = 0; kk < 4; ++kk) {
            bf16x8 a[4];
#pragma unroll
            for (int tm = 0; tm < 4; ++tm)
                a[tm] = *(const bf16x8*)&Xs[tm * 16 + l16][kk * 32 + quad * 8];
            bf16x8 bb[2];
#pragma unroll
            for (int nt = 0; nt < 2; ++nt) {
                int n = hbase + ncol0 + nt * 16 + l16;
                bb[nt] = *(const bf16x8*)(W1t + (size_t)n * F2 + kk * 32 + quad * 8);
            }
#pragma unroll
            for (int tm = 0; tm < 4; ++tm)
#pragma unroll
                for (int nt = 0; nt < 2; ++nt)
                    acc1[tm][nt] = __builtin_amdgcn_mfma_f32_16x16x32_bf16(
                        a[tm], bb[nt], acc1[tm][nt], 0, 0, 0);
        }
#pragma unroll
        for (int nt = 0; nt < 2; ++nt) {
            float bias = b1[hbase + ncol0 + nt * 16 + l16];
#pragma unroll
            for (int tm = 0; tm < 4; ++tm)
#pragma unroll
                for (int r = 0; r < 4; ++r) {
                    float v = acc1[tm][nt][r] + bias;
                    Hs[tm * 16 + quad * 4 + r][ncol0 + nt * 16 + l16] = (__bf16)gelu_fast(v);
                }
        }
        __syncthreads();
#pragma unroll
        for (int kk = 0; kk < 4; ++kk) {
            bf16x8 a[4];
#pragma unroll
            for (int tm = 0; tm < 4; ++tm)
                a[tm] = *(const bf16x8*)&Hs[tm * 16 + l16][kk * 32 + quad * 8];
            bf16x8 bb[2];
#pragma unroll
            for (int nt = 0; nt < 2; ++nt) {
                int p = ncol0 + nt * 16 + l16;
                bb[nt] = *(const bf16x8*)(W2t + (size_t)p * H2 + hbase + kk * 32 + quad * 8);
            }
#pragma unroll
            for (int tm = 0; tm < 4; ++tm)
#pragma unroll
                for (int nt = 0; nt < 2; ++nt)
                    acc2[tm][nt] = __builtin_amdgcn_mfma_f32_16x16x32_bf16(
                        a[tm], bb[nt], acc2[tm][nt], 0, 0, 0);
        }
        __syncthreads();
    }
#pragma unroll
    for (int nt = 0; nt < 2; ++nt) {
        const int p = ncol0 + nt * 16 + l16;
        const float bias = b2[p];
#pragma unroll
        for (int tm = 0; tm < 4; ++tm) {
            float s = 0.f;
#pragma unroll
            for (int r = 0; r < 4; ++r) s += gelu_fast(acc2[tm][nt][r] + bias);
            s += __shfl_xor(s, 16, 64);
            s += __shfl_xor(s, 32, 64);
            if (quad == 0) {
                int gq = gq0 + tm;
                out[(size_t)gq * PP + p] = s * 0.0625f;
            }
        }
    }
}

extern "C" void kernel_launch(void* const* d_in, const int* in_sizes, int n_in,
                              void* d_out, int out_size, void* d_ws, size_t ws_size,
                              hipStream_t stream) {
    const float* points   = (const float*)d_in[0];
    const float* features = (const float*)d_in[1];
    const float* W1 = (const float*)d_in[2];
    const float* b1 = (const float*)d_in[3];
    const float* W2 = (const float*)d_in[4];
    const float* b2 = (const float*)d_in[5];
    float* out = (float*)d_out;

    const size_t IDX_B  = (size_t)BB * NN * KNN * 4;   // 2 MB
    const size_t WCAT_B = 512 * 64 * 2;                // 64 KB
    const size_t W2T_B  = 128 * 256 * 2;               // 64 KB
    const size_t G_B    = (size_t)BB * NN * H2 * 2;    // 16 MB
    const size_t QF32_B = (size_t)BB * NN * H2 * 4;    // 32 MB
    const size_t QBF_B  = (size_t)BB * NN * H2 * 2;    // 16 MB

    int* knn_idx = (int*)d_ws;
    char* p = (char*)d_ws + IDX_B;
    __bf16* WcatT = (__bf16*)p;            p += WCAT_B;
    __bf16* W2t   = (__bf16*)p;            p += W2T_B;
    __bf16* Gall  = (__bf16*)p;            p += G_B;
    void*   Qall  = (void*)p;

    const size_t need_f32  = IDX_B + WCAT_B + W2T_B + G_B + QF32_B;
    const size_t need_bf16 = IDX_B + WCAT_B + W2T_B + G_B + QBF_B;

    knn_select<<<BB * 128, 512, 0, stream>>>(points, knn_idx);

    if (ws_size >= need_f32) {
        prep_small<<<128, 256, 0, stream>>>(W1, W2, WcatT, W2t);
        gq_gemm<true><<<2048, 256, 0, stream>>>(features, WcatT, b1, Gall, Qall);
        fused_mlp2<true><<<BB * NN / 4, 256, 0, stream>>>(Gall, Qall, knn_idx, W2t, b2, out);
    } else if (ws_size >= need_bf16) {
        prep_small<<<128, 256, 0, stream>>>(W1, W2, WcatT, W2t);
        gq_gemm<false><<<2048, 256, 0, stream>>>(features, WcatT, b1, Gall, Qall);
        fused_mlp2<false><<<BB * NN / 4, 256, 0, stream>>>(Gall, Qall, knn_idx, W2t, b2, out);
    } else {
        // fallback: round-3 path (needs only 2.13 MB)
        __bf16* W1t_f = (__bf16*)((char*)d_ws + IDX_B);
        __bf16* W2t_f = W1t_f + H2 * F2;
        prep_weights<<<128, 256, 0, stream>>>(W1, W2, W1t_f, W2t_f);
        mlp_mfma<<<BB * NN / 4, 256, 0, stream>>>(features, knn_idx, W1t_f, b1, W2t_f, b2, out);
    }
}

// Round 5
// 213.890 us; speedup vs baseline: 1.9418x; 1.9418x over previous
//
#include <hip/hip_runtime.h>
#include <math.h>

#define BB 32
#define NN 1024
#define FF 64
#define PP 128
#define KNN 16
#define H2 256  // 2P
#define F2 128  // 2F
#define KSEL 17
#define SVCAP 272

typedef float f32x4 __attribute__((ext_vector_type(4)));
typedef __bf16 bf16x8 __attribute__((ext_vector_type(8)));

__device__ __forceinline__ float gelu_fast(float x) {
    float u = x * (1.0f + 0.044715f * x * x);
    float e = __builtin_amdgcn_exp2f(-2.3022115f * u);
    return x * __builtin_amdgcn_rcpf(1.0f + e);
}

// ---------------- Kernel A: set-based kNN via radix ballot-select -------------------
__global__ __launch_bounds__(512, 8) void knn_select(const float* __restrict__ points,
                                                     int* __restrict__ idx_out) {
    __shared__ float4 pts[NN];
    __shared__ unsigned sv_val[8][SVCAP];
    __shared__ unsigned sv_idx[8][SVCAP];
    __shared__ unsigned tie_idx[8][64];

    const int t = threadIdx.x;
    const int w = t >> 6, lane = t & 63;
    const int b = blockIdx.x >> 7;
    const int q0 = (blockIdx.x & 127) * 8;
    const float* pb = points + (size_t)b * NN * 3;
    const unsigned long long lt = (1ull << lane) - 1ull;

    for (int i = t; i < NN; i += 512) {
        float x = pb[3 * i], y = pb[3 * i + 1], z = pb[3 * i + 2];
        float r = __fadd_rn(__fadd_rn(__fmul_rn(x, x), __fmul_rn(y, y)), __fmul_rn(z, z));
        pts[i] = make_float4(x, y, z, r);
    }
    __syncthreads();

    const int qn = q0 + w;
    const int gq = b * NN + qn;
    const float4 qp = pts[qn];

    float D[16];
#pragma unroll
    for (int j = 0; j < 16; ++j) {
        float4 c = pts[j * 64 + lane];
        float dot = __fadd_rn(__fadd_rn(__fmul_rn(qp.x, c.x), __fmul_rn(qp.y, c.y)),
                              __fmul_rn(qp.z, c.z));
        D[j] = __fadd_rn(__fadd_rn(__fsub_rn(qp.w, __fmul_rn(2.0f, dot)), c.w), 1e-5f);
    }

    float mnf = D[0];
#pragma unroll
    for (int j = 1; j < 16; ++j) mnf = fminf(mnf, D[j]);
    const unsigned mbits = __float_as_uint(mnf);

    unsigned T = 0;
#pragma unroll
    for (int bit = 31; bit >= 0; --bit) {
        unsigned cand = T | (1u << bit);
        int cnt = __popcll(__ballot(mbits < cand));
        if (cnt < KSEL) T = cand;
    }

    unsigned base = 0;
#pragma unroll
    for (int j = 0; j < 16; ++j) {
        unsigned vb = __float_as_uint(D[j]);
        bool keep = (vb <= T);
        unsigned long long m = __ballot(keep);
        if (keep) {
            unsigned pos = base + (unsigned)__popcll(m & lt);
            if (pos < SVCAP) { sv_val[w][pos] = vb; sv_idx[w][pos] = j * 64 + lane; }
        }
        base += (unsigned)__popcll(m);
    }
    unsigned C = base > SVCAP ? SVCAP : base;
    const int S = (int)((C + 63) >> 6);

    unsigned Ts = 0;
    if (S == 1) {
        unsigned xv0 = (lane < (int)C) ? sv_val[w][lane] : 0xFFFFFFFFu;
#pragma unroll
        for (int bit = 31; bit >= 0; --bit) {
            unsigned cand = Ts | (1u << bit);
            int cnt = __popcll(__ballot(xv0 < cand));
            if (cnt < KSEL) Ts = cand;
        }
    } else {
        for (int bit = 31; bit >= 0; --bit) {
            unsigned cand = Ts | (1u << bit);
            int cnt = 0;
            for (int s = 0; s < S; ++s) {
                int i = s * 64 + lane;
                unsigned vb = (i < (int)C) ? sv_val[w][i] : 0xFFFFFFFFu;
                cnt += __popcll(__ballot(vb < cand));
            }
            if (cnt < KSEL) Ts = cand;
        }
    }

    int L = 0;
    for (int s = 0; s < S; ++s) {
        int i = s * 64 + lane;
        unsigned vb = (i < (int)C) ? sv_val[w][i] : 0xFFFFFFFFu;
        L += __popcll(__ballot(vb < Ts));
    }
    const int need = KSEL - L;

    unsigned vmin_l = 0xFFFFFFFFu;
    for (int s = 0; s < S; ++s) {
        int i = s * 64 + lane;
        unsigned vb = (i < (int)C) ? sv_val[w][i] : 0xFFFFFFFFu;
        vmin_l = vmin_l < vb ? vmin_l : vb;
    }
#pragma unroll
    for (int off = 32; off >= 1; off >>= 1) {
        unsigned o2 = __shfl_xor(vmin_l, off, 64);
        vmin_l = vmin_l < o2 ? vmin_l : o2;
    }
    const unsigned Vmin = vmin_l;
    unsigned imin_l = 0xFFFFFFFFu;
    for (int s = 0; s < S; ++s) {
        int i = s * 64 + lane;
        unsigned vb = (i < (int)C) ? sv_val[w][i] : 0xFFFFFFFFu;
        unsigned mi = (i < (int)C) ? sv_idx[w][i] : 0xFFFFFFFFu;
        if (vb == Vmin && mi < imin_l) imin_l = mi;
    }
#pragma unroll
    for (int off = 32; off >= 1; off >>= 1) {
        unsigned o2 = __shfl_xor(imin_l, off, 64);
        imin_l = imin_l < o2 ? imin_l : o2;
    }
    const unsigned dropIdx = imin_l;

    int* o = idx_out + (size_t)gq * KNN;
    unsigned wbase = 0, tbase = 0;
    for (int s = 0; s < S; ++s) {
        int i = s * 64 + lane;
        unsigned vb = (i < (int)C) ? sv_val[w][i] : 0xFFFFFFFFu;
        unsigned mi = (i < (int)C) ? sv_idx[w][i] : 0xFFFFFFFFu;
        bool wk = (vb < Ts) && (mi != dropIdx);
        unsigned long long wm = __ballot(wk);
        if (wk) o[wbase + (unsigned)__popcll(wm & lt)] = (int)mi;
        wbase += (unsigned)__popcll(wm);
        bool tk = (vb == Ts);
        unsigned long long tm2 = __ballot(tk);
        if (tk) {
            unsigned tp = tbase + (unsigned)__popcll(tm2 & lt);
            if (tp < 64) tie_idx[w][tp] = mi;
        }
        tbase += (unsigned)__popcll(tm2);
    }
    unsigned tc = tbase > 64 ? 64 : tbase;
    if ((int)tc == need) {
        bool tk = (lane < (int)tc);
        unsigned mi2 = tk ? tie_idx[w][lane] : 0xFFFFFFFFu;
        tk = tk && (mi2 != dropIdx);
        unsigned long long m3 = __ballot(tk);
        if (tk) o[wbase + (unsigned)__popcll(m3 & lt)] = (int)mi2;
    } else if (lane == 0) {
        unsigned pos = wbase;
        for (int r = 0; r < need; ++r) {
            unsigned best = 0xFFFFFFFFu; int bj = 0;
            for (int j2 = 0; j2 < (int)tc; ++j2) {
                unsigned mi = tie_idx[w][j2];
                if (mi < best) { best = mi; bj = j2; }
            }
            tie_idx[w][bj] = 0xFFFFFFFFu;
            if (best != dropIdx) o[pos++] = (int)best;
        }
    }
}

// ---------------- prep_frag: build fragment-swizzled Wcf (gq_gemm B) + W2f (fused B) -
// Wcf: frag(n_tile 0..31, kk 0..1, lane): WcatT[n_tile*16+l16][kk*32+quad*8+j]
//   where WcatT[n][k] = (n<256) ? W1[k][n] : W1[64+k][n-256]-W1[k][n-256]
// W2f: frag(kk8 0..7, nt 0..7, lane): W2[kk8*32+quad*8+j][nt*16+l16]
__global__ __launch_bounds__(256) void prep_frag(const float* __restrict__ W1,
                                                 const float* __restrict__ W2,
                                                 __bf16* __restrict__ Wcf,
                                                 __bf16* __restrict__ W2f) {
    int tid = blockIdx.x * 256 + threadIdx.x;   // 0..8191
    if (tid < 4096) {
        const int lane = tid & 63, quad = lane >> 4, l16 = lane & 15;
        const int kk = (tid >> 6) & 1, n_tile = tid >> 7;
        const int n = n_tile * 16 + l16;
        const int kb = kk * 32 + quad * 8;
        bf16x8 v;
#pragma unroll
        for (int j = 0; j < 8; ++j) {
            const int k = kb + j;
            float x = (n < 256) ? W1[k * 256 + n]
                                : (W1[(64 + k) * 256 + (n - 256)] - W1[k * 256 + (n - 256)]);
            v[j] = (__bf16)x;
        }
        *(bf16x8*)(Wcf + (size_t)tid * 8) = v;
    } else {
        const int t2 = tid - 4096;
        const int lane = t2 & 63, quad = lane >> 4, l16 = lane & 15;
        const int nt = (t2 >> 6) & 7, kk8 = t2 >> 9;
        const int p = nt * 16 + l16;
        const int hb = kk8 * 32 + quad * 8;
        bf16x8 v;
#pragma unroll
        for (int j = 0; j < 8; ++j) v[j] = (__bf16)W2[(size_t)(hb + j) * PP + p];
        *(bf16x8*)(W2f + (size_t)t2 * 8) = v;
    }
}

// ---------------- gq_gemm: G = feat@W1a (bf16), Q = feat@Wd + b1 (bf16) -------------
// M=32768, K=64, N=512. Block = 16 rows, wave = 16x128 strip. LDS-transposed stores.
__global__ __launch_bounds__(256, 4) void gq_gemm(const float* __restrict__ feat,
                                                  const __bf16* __restrict__ Wcf,
                                                  const float* __restrict__ b1,
                                                  __bf16* __restrict__ Gall,
                                                  __bf16* __restrict__ Qall) {
    __shared__ __align__(16) __bf16 st[4][16][136];
    const int t = threadIdx.x, w = t >> 6, lane = t & 63;
    const int quad = lane >> 4, l16 = lane & 15;
    const int m0 = blockIdx.x * 16;

    bf16x8 a[2];
#pragma unroll
    for (int kk = 0; kk < 2; ++kk) {
        const float* ap = feat + (size_t)(m0 + l16) * 64 + kk * 32 + quad * 8;
        float4 a0 = *(const float4*)ap, a1 = *(const float4*)(ap + 4);
        bf16x8 v;
        v[0] = (__bf16)a0.x; v[1] = (__bf16)a0.y; v[2] = (__bf16)a0.z; v[3] = (__bf16)a0.w;
        v[4] = (__bf16)a1.x; v[5] = (__bf16)a1.y; v[6] = (__bf16)a1.z; v[7] = (__bf16)a1.w;
        a[kk] = v;
    }
    f32x4 acc[8];
#pragma unroll
    for (int nt = 0; nt < 8; ++nt) acc[nt] = (f32x4){0.f, 0.f, 0.f, 0.f};
#pragma unroll
    for (int kk = 0; kk < 2; ++kk)
#pragma unroll
        for (int nt = 0; nt < 8; ++nt) {
            bf16x8 bf = *(const bf16x8*)(Wcf + (size_t)(((w * 8 + nt) * 2 + kk) * 64 + lane) * 8);
            acc[nt] = __builtin_amdgcn_mfma_f32_16x16x32_bf16(a[kk], bf, acc[nt], 0, 0, 0);
        }

    const bool isQ = (w >= 2);
#pragma unroll
    for (int nt = 0; nt < 8; ++nt) {
        const int col = nt * 16 + l16;
        const float bias = isQ ? b1[(w - 2) * 128 + col] : 0.f;
#pragma unroll
        for (int r = 0; r < 4; ++r)
            st[w][quad * 4 + r][col] = (__bf16)(acc[nt][r] + bias);
    }
    __syncthreads();

    const int row = lane >> 2, c = lane & 3;
    const int m = m0 + row;
#pragma unroll
    for (int i = 0; i < 4; ++i) {
        const int col = c * 32 + i * 8;
        bf16x8 v = *(const bf16x8*)&st[w][row][col];
        if (!isQ) *(bf16x8*)(Gall + (size_t)m * H2 + w * 128 + col) = v;
        else      *(bf16x8*)(Qall + (size_t)m * H2 + (w - 2) * 128 + col) = v;
    }
}

// ---------------- fused_mlp3: out = mean_k gelu(gelu(G[idx]+Q) @ W2 + b2) -----------
// Block = 512 thr (8 waves), W2f staged in LDS once. Wave: 2 iters x 2 queries.
__global__ __launch_bounds__(512, 4) void fused_mlp3(const __bf16* __restrict__ Gall,
                                                     const __bf16* __restrict__ Qall,
                                                     const int* __restrict__ knn_idx,
                                                     const __bf16* __restrict__ W2f,
                                                     const float* __restrict__ b2,
                                                     float* __restrict__ out) {
    __shared__ __align__(16) __bf16 w2s[32768];   // 64 KB, fragment order
    const int t = threadIdx.x, w = t >> 6, lane = t & 63;
    const int quad = lane >> 4, l16 = lane & 15;

#pragma unroll
    for (int i = 0; i < 8; ++i) {
        bf16x8 v = *(const bf16x8*)(W2f + (size_t)(i * 512 + t) * 8);
        *(bf16x8*)&w2s[(size_t)(i * 512 + t) * 8] = v;
    }
    __syncthreads();

    const int wave_id = blockIdx.x * 8 + w;

    float bias[8];
#pragma unroll
    for (int nt = 0; nt < 8; ++nt) bias[nt] = b2[nt * 16 + l16];

#pragma unroll
    for (int it = 0; it < 2; ++it) {
        const int q0 = wave_id * 4 + it * 2;     // queries q0, q0+1
        const int b = q0 >> 10;
        const int nb0 = knn_idx[q0 * KNN + l16];
        const int nb1 = knn_idx[(q0 + 1) * KNN + l16];
        const __bf16* g0 = Gall + ((size_t)(b << 10) + nb0) * H2;
        const __bf16* g1 = Gall + ((size_t)(b << 10) + nb1) * H2;
        const __bf16* qq0 = Qall + (size_t)q0 * H2;
        const __bf16* qq1 = qq0 + H2;

        f32x4 acc[2][8];
#pragma unroll
        for (int tm = 0; tm < 2; ++tm)
#pragma unroll
            for (int nt = 0; nt < 8; ++nt) acc[tm][nt] = (f32x4){0.f, 0.f, 0.f, 0.f};

#pragma unroll
        for (int kk8 = 0; kk8 < 8; ++kk8) {
            const int ho = kk8 * 32 + quad * 8;
            bf16x8 gA = *(const bf16x8*)(g0 + ho);
            bf16x8 qA = *(const bf16x8*)(qq0 + ho);
            bf16x8 gB = *(const bf16x8*)(g1 + ho);
            bf16x8 qB = *(const bf16x8*)(qq1 + ho);
            bf16x8 a0, a1;
#pragma unroll
            for (int j = 0; j < 8; ++j) {
                a0[j] = (__bf16)gelu_fast((float)gA[j] + (float)qA[j]);
                a1[j] = (__bf16)gelu_fast((float)gB[j] + (float)qB[j]);
            }
            const __bf16* bb = &w2s[kk8 * 8 * 512 + lane * 8];
#pragma unroll
            for (int nt = 0; nt < 8; ++nt) {
                bf16x8 bf = *(const bf16x8*)(bb + nt * 512);
                acc[0][nt] = __builtin_amdgcn_mfma_f32_16x16x32_bf16(a0, bf, acc[0][nt], 0, 0, 0);
                acc[1][nt] = __builtin_amdgcn_mfma_f32_16x16x32_bf16(a1, bf, acc[1][nt], 0, 0, 0);
            }
        }

#pragma unroll
        for (int tm = 0; tm < 2; ++tm)
#pragma unroll
            for (int nt = 0; nt < 8; ++nt) {
                float s = 0.f;
#pragma unroll
                for (int r = 0; r < 4; ++r) s += gelu_fast(acc[tm][nt][r] + bias[nt]);
                s += __shfl_xor(s, 16, 64);
                s += __shfl_xor(s, 32, 64);
                if (quad == 0)
                    out[(size_t)(q0 + tm) * PP + nt * 16 + l16] = s * 0.0625f;
            }
    }
}

extern "C" void kernel_launch(void* const* d_in, const int* in_sizes, int n_in,
                              void* d_out, int out_size, void* d_ws, size_t ws_size,
                              hipStream_t stream) {
    const float* points   = (const float*)d_in[0];
    const float* features = (const float*)d_in[1];
    const float* W1 = (const float*)d_in[2];
    const float* b1 = (const float*)d_in[3];
    const float* W2 = (const float*)d_in[4];
    const float* b2 = (const float*)d_in[5];
    float* out = (float*)d_out;

    const size_t IDX_B  = (size_t)BB * NN * KNN * 4;   // 2 MB
    const size_t WCF_B  = 512 * 64 * 2;                // 64 KB
    const size_t W2F_B  = 256 * 128 * 2;               // 64 KB
    const size_t G_B    = (size_t)BB * NN * H2 * 2;    // 16 MB

    int* knn_idx = (int*)d_ws;
    char* p = (char*)d_ws + IDX_B;
    __bf16* Wcf  = (__bf16*)p;  p += WCF_B;
    __bf16* W2f  = (__bf16*)p;  p += W2F_B;
    __bf16* Gall = (__bf16*)p;  p += G_B;
    __bf16* Qall = (__bf16*)p;                         // 16 MB -> total ~34.1 MB

    prep_frag<<<32, 256, 0, stream>>>(W1, W2, Wcf, W2f);
    knn_select<<<BB * 128, 512, 0, stream>>>(points, knn_idx);
    gq_gemm<<<2048, 256, 0, stream>>>(features, Wcf, b1, Gall, Qall);
    fused_mlp3<<<1024, 512, 0, stream>>>(Gall, Qall, knn_idx, W2f, b2, out);
}